// Round 7
// baseline (137.102 us; speedup 1.0000x reference)
//
#include <hip/hip_runtime.h>
#include <math.h>
#include <limits.h>

#define BB 4
#define SS 2048
#define HH 768
#define MAXSEG 256
#define NUM_POS (BB*(SS/4))   // 2048
#define NEG_BIG -1000000000.0f
#define NSEGSUM (BB*MAXSEG)   // 1024
#define NWCAST  576           // 768*768/4 float4s / 256 threads

typedef _Float16 f16x8 __attribute__((ext_vector_type(8)));
typedef _Float16 f16x4 __attribute__((ext_vector_type(4)));
typedef float    f32x4 __attribute__((ext_vector_type(4)));

// 256-thread exclusive scan (4 waves, shfl + LDS). Caller must __syncthreads()
// between consecutive uses (sWave reuse).
__device__ __forceinline__ int blockExclScan(int v, int* sWave, int lane, int wid)
{
  int x = v;
  #pragma unroll
  for (int off = 1; off < 64; off <<= 1) {
    int y = __shfl_up(x, off, 64);
    if (lane >= off) x += y;
  }
  if (lane == 63) sWave[wid] = x;
  __syncthreads();
  int base = 0;
  for (int w = 0; w < wid; w++) base += sWave[w];
  return base + x - v;
}

// ---------------------------------------------------------------------------
// Kernel 1 (front): three independent roles, one dispatch.
//   blocks [0,1024): segment sums with INLINE boundary computation (each block
//                    re-scans its batch's indicator row; no dependency on scan)
//   blocks [1024,1028): per-batch scan -> seg_id, positive buckets, accum zero
//   blocks [1028,1604): W f32->f16 cast
// ---------------------------------------------------------------------------
__global__ __launch_bounds__(256) void k_front(
    const float* __restrict__ es, const float* __restrict__ W,
    const int* __restrict__ ind, const int* __restrict__ clc,
    _Float16* __restrict__ segsum_h, _Float16* __restrict__ Wh,
    int* __restrict__ seg_id, int* __restrict__ pos_cnt,
    int* __restrict__ allowCnt, int* __restrict__ firstAllow,
    int* __restrict__ posSegOff, int* __restrict__ posSeg,
    float* __restrict__ accum, int* __restrict__ counter)
{
  int t = threadIdx.x;
  int lane = t & 63, wid = t >> 6;
  int blk = blockIdx.x;

  __shared__ int sInd[SS];
  __shared__ int sWave[4];
  __shared__ int sAC[MAXSEG];
  __shared__ int sFA[MAXSEG];
  __shared__ int sStEn[2];

  if (blk >= NSEGSUM + BB) {
    // ---- W cast ----
    int idx = (blk - NSEGSUM - BB)*256 + t;     // float4 index; 147456 total
    float4 v = ((const float4*)W)[idx];
    f16x4 h;
    h[0] = (_Float16)v.x; h[1] = (_Float16)v.y;
    h[2] = (_Float16)v.z; h[3] = (_Float16)v.w;
    *(f16x4*)(Wh + (size_t)idx*4) = h;
    return;
  }

  if (blk < NSEGSUM) {
    // ---- segment sum for (b, s), boundaries computed inline ----
    int b = blk >> 8, s = blk & 255;
    for (int i = t; i < SS; i += 256) sInd[i] = ind[b*SS + i];
    if (t == 0) { sStEn[0] = SS; sStEn[1] = SS; }
    __syncthreads();
    int i0 = t * 8;
    int f[8]; int lsum = 0;
    #pragma unroll
    for (int u = 0; u < 8; u++) {
      int i = i0 + u;
      f[u] = (i == 0) ? 0 : (sInd[i] != sInd[i-1]);
      lsum += f[u];
    }
    int run = blockExclScan(lsum, sWave, lane, wid);
    #pragma unroll
    for (int u = 0; u < 8; u++) {
      int i = i0 + u;
      run += f[u];
      if (run == s   && (f[u] || i == 0)) sStEn[0] = i;   // start of segment s
      if (run == s+1 && f[u])             sStEn[1] = i;   // start of segment s+1
    }
    __syncthreads();
    int st = sStEn[0], en = sStEn[1];
    float4 acc = {0.f, 0.f, 0.f, 0.f};
    if (t < 192 && st < SS) {          // st==SS => segment doesn't exist -> zeros
      const float* basep = es + (size_t)b*SS*HH + t*4;
      for (int i = st; i < en; i++) {
        float4 v = *(const float4*)(basep + (size_t)i*HH);
        acc.x += v.x; acc.y += v.y; acc.z += v.z; acc.w += v.w;
      }
    }
    if (t < 192) {
      f16x4 h;
      h[0] = (_Float16)acc.x; h[1] = (_Float16)acc.y;
      h[2] = (_Float16)acc.z; h[3] = (_Float16)acc.w;
      *(f16x4*)(segsum_h + ((size_t)b*MAXSEG + s)*HH + t*4) = h;
    }
    return;
  }

  // ---- per-batch scan (blocks 1024..1027) ----
  int b = blk - NSEGSUM;
  if (b == 0 && t < 4) accum[t] = 0.f;
  if (b == 0 && t == 4) *counter = 0;
  for (int i = t; i < SS; i += 256) sInd[i] = ind[b*SS + i];
  sAC[t] = 0; sFA[t] = INT_MAX;
  __syncthreads();

  int i0 = t * 8;
  int f[8], cv[8];
  int lsum = 0;
  #pragma unroll
  for (int u = 0; u < 8; u++) {
    int i = i0 + u;
    f[u] = (i == 0) ? 0 : (sInd[i] != sInd[i-1]);
    cv[u] = clc[b*SS + i];
    lsum += f[u];
  }
  int run = blockExclScan(lsum, sWave, lane, wid);
  int rid[8];
  #pragma unroll
  for (int u = 0; u < 8; u++) {
    run += f[u];
    rid[u] = run;
    seg_id[b*SS + i0 + u] = run;
  }

  // allowed-column stats per segment
  #pragma unroll
  for (int u = 0; u < 8; u++) {
    if (cv[u] < 0) {
      atomicAdd(&sAC[rid[u]], 1);
      atomicMin(&sFA[rid[u]], i0 + u);
    }
  }
  __syncthreads();
  allowCnt[b*MAXSEG + t]   = sAC[t];
  firstAllow[b*MAXSEG + t] = sFA[t];
  __syncthreads();

  // positive ranks (local k within batch)
  int p[8], kk[8];
  int psum = 0;
  #pragma unroll
  for (int u = 0; u < 8; u++) { p[u] = (cv[u] > 0) ? 1 : 0; psum += p[u]; }
  int rank = blockExclScan(psum, sWave, lane, wid);
  #pragma unroll
  for (int u = 0; u < 8; u++) {
    kk[u] = rank;
    if (p[u]) rank++;
  }
  if (t == 255) pos_cnt[b] = rank;
  __syncthreads();

  // bucket positives by segment
  sAC[t] = 0;
  __syncthreads();
  #pragma unroll
  for (int u = 0; u < 8; u++) if (p[u]) atomicAdd(&sAC[rid[u]], 1);
  __syncthreads();
  int cnt = sAC[t];
  int off = blockExclScan(cnt, sWave, lane, wid);
  posSegOff[b*(MAXSEG+1) + t] = off;
  if (t == 255) posSegOff[b*(MAXSEG+1) + 256] = off + cnt;
  __syncthreads();
  sFA[t] = off;                 // scatter cursor
  __syncthreads();
  #pragma unroll
  for (int u = 0; u < 8; u++) {
    if (p[u]) {
      int pos = atomicAdd(&sFA[rid[u]], 1);
      posSeg[b*SS + pos] = (kk[u] << 16) | (i0 + u);
    }
  }
}

// ---------------------------------------------------------------------------
// Kernel 2: U = tanh(segsum @ W^T + bias), f16 MFMA, direct-global fragments.
// Wave = 32x32 tile (2x2 of 16x16x32). 768 tiles -> 192 blocks.
// ---------------------------------------------------------------------------
__global__ __launch_bounds__(256) void k_gemmU(
    const _Float16* __restrict__ Ah, const _Float16* __restrict__ Wh,
    const float* __restrict__ bias, _Float16* __restrict__ Uh)
{
  int tid = threadIdx.x;
  int w = tid >> 6, lane = tid & 63;
  int tile = blockIdx.x*4 + w;          // 0..767 over 32 x 24 tiles
  int tm = tile / 24, tn = tile % 24;
  int rb = tm*32, cb = tn*32;
  int m0 = lane & 15, quad = lane >> 4;
  const _Float16* A0 = Ah + (size_t)(rb + m0)*HH + quad*8;
  const _Float16* A1 = A0 + (size_t)16*HH;
  const _Float16* B0 = Wh + (size_t)(cb + m0)*HH + quad*8;
  const _Float16* B1 = B0 + (size_t)16*HH;
  f32x4 acc00 = {0.f,0.f,0.f,0.f}, acc01 = {0.f,0.f,0.f,0.f};
  f32x4 acc10 = {0.f,0.f,0.f,0.f}, acc11 = {0.f,0.f,0.f,0.f};
  #pragma unroll 4
  for (int k0 = 0; k0 < HH; k0 += 32) {
    f16x8 a0 = *(const f16x8*)(A0 + k0);
    f16x8 a1 = *(const f16x8*)(A1 + k0);
    f16x8 b0 = *(const f16x8*)(B0 + k0);
    f16x8 b1 = *(const f16x8*)(B1 + k0);
    acc00 = __builtin_amdgcn_mfma_f32_16x16x32_f16(a0, b0, acc00, 0, 0, 0);
    acc01 = __builtin_amdgcn_mfma_f32_16x16x32_f16(a0, b1, acc01, 0, 0, 0);
    acc10 = __builtin_amdgcn_mfma_f32_16x16x32_f16(a1, b0, acc10, 0, 0, 0);
    acc11 = __builtin_amdgcn_mfma_f32_16x16x32_f16(a1, b1, acc11, 0, 0, 0);
  }
  float bc0 = bias[cb + m0], bc1 = bias[cb + 16 + m0];
  int r0 = rb + quad*4;
  #pragma unroll
  for (int i = 0; i < 4; i++) {
    Uh[(size_t)(r0+i)*HH    + cb + m0]      = (_Float16)tanhf(acc00[i] + bc0);
    Uh[(size_t)(r0+i)*HH    + cb + 16 + m0] = (_Float16)tanhf(acc01[i] + bc1);
    Uh[(size_t)(r0+16+i)*HH + cb + m0]      = (_Float16)tanhf(acc10[i] + bc0);
    Uh[(size_t)(r0+16+i)*HH + cb + 16 + m0] = (_Float16)tanhf(acc11[i] + bc1);
  }
}

// ---------------------------------------------------------------------------
// Kernel 3: Gram slab (16 rows x 256 cols) via MFMA into LDS, then fused
// lse/argmax/positive-loss tail on the slab. 64 blocks (4 batches x 16 slabs).
// G never touches global memory.
// ---------------------------------------------------------------------------
__global__ __launch_bounds__(256) void k_gramtail(
    const _Float16* __restrict__ Uh, const int* __restrict__ seg_id,
    const int* __restrict__ clc, const int* __restrict__ pos_cnt,
    const int* __restrict__ allowCnt, const int* __restrict__ firstAllow,
    const int* __restrict__ posSegOff, const int* __restrict__ posSeg,
    float* __restrict__ accum, int* __restrict__ counter,
    float* __restrict__ out)
{
  __shared__ float Gs[16][260];     // +4 pad: spreads the 4-quad row stride
  __shared__ float sP[4][4];
  int t = threadIdx.x;
  int lane = t & 63, wid = t >> 6;
  int b = blockIdx.x >> 4;
  int rb = (blockIdx.x & 15) * 16;  // slab rows = segments rb..rb+15
  int m0 = lane & 15, quad = lane >> 4;
  const _Float16* Ub = Uh + (size_t)b*MAXSEG*HH;
  const _Float16* Ap = Ub + (size_t)(rb + m0)*HH + quad*8;

  // ---- Gram slab: wave wid computes col-tiles (wid*4 .. wid*4+3) ----
  #pragma unroll
  for (int ct = 0; ct < 4; ct++) {
    int cb = (wid*4 + ct)*16;
    const _Float16* Bp = Ub + (size_t)(cb + m0)*HH + quad*8;
    f32x4 acc = {0.f,0.f,0.f,0.f};
    #pragma unroll 4
    for (int k0 = 0; k0 < HH; k0 += 32) {
      f16x8 a  = *(const f16x8*)(Ap + k0);
      f16x8 bb = *(const f16x8*)(Bp + k0);
      acc = __builtin_amdgcn_mfma_f32_16x16x32_f16(a, bb, acc, 0, 0, 0);
    }
    #pragma unroll
    for (int i = 0; i < 4; i++)
      Gs[quad*4 + i][cb + m0] = acc[i];
  }
  __syncthreads();

  // ---- tail: wave wid handles slab rows wid*4 .. wid*4+3 ----
  const int* ac = allowCnt + b*MAXSEG;
  const int* fa = firstAllow + b*MAXSEG;
  int base_b = 0;
  for (int x = 0; x < b; x++) base_b += pos_cnt[x];
  float l0 = 0.f, c0 = 0.f, l1 = 0.f, c1 = 0.f;

  #pragma unroll
  for (int q2 = 0; q2 < 4; q2++) {
    int row = wid*4 + q2;
    int si = rb + row;
    float gv[4]; int av[4], fv[4];
    #pragma unroll
    for (int q = 0; q < 4; q++) {
      int s2 = lane + 64*q;
      gv[q] = Gs[row][s2]; av[q] = ac[s2]; fv[q] = fa[s2];
    }
    // max over allowed segments
    float m = -INFINITY;
    #pragma unroll
    for (int q = 0; q < 4; q++) if (av[q] > 0) m = fmaxf(m, gv[q]);
    #pragma unroll
    for (int off = 32; off > 0; off >>= 1) m = fmaxf(m, __shfl_xor(m, off, 64));
    // weighted exp-sum (masked cols underflow to exactly 0, as in reference)
    float s = 0.f;
    #pragma unroll
    for (int q = 0; q < 4; q++) if (av[q] > 0) s += (float)av[q] * expf(gv[q] - m);
    #pragma unroll
    for (int off = 32; off > 0; off >>= 1) s += __shfl_xor(s, off, 64);
    // first-occurrence argmax
    float bv = -INFINITY; int bi = INT_MAX;
    #pragma unroll
    for (int q = 0; q < 4; q++) {
      if (av[q] > 0 && (gv[q] > bv || (gv[q] == bv && fv[q] < bi))) { bv = gv[q]; bi = fv[q]; }
    }
    #pragma unroll
    for (int off = 32; off > 0; off >>= 1) {
      float ov = __shfl_xor(bv, off, 64);
      int   oi = __shfl_xor(bi, off, 64);
      if (ov > bv || (ov == bv && oi < bi)) { bv = ov; bi = oi; }
    }
    float lseV = m + logf(s);       // NaN only for nonexistent segments (unused)

    // positives belonging to segment si (empty for nonexistent segments)
    int st = posSegOff[b*(MAXSEG+1) + si];
    int en = posSegOff[b*(MAXSEG+1) + si + 1];
    for (int pp = st + lane; pp < en; pp += 64) {
      int e = posSeg[b*SS + pp];
      int i = e & 0xFFFF, k = e >> 16;
      int L = clc[b*SS + i];
      int sL = seg_id[b*SS + L];
      float vL = Gs[row][sL] + (clc[b*SS + L] < 0 ? 0.0f : NEG_BIG);
      float loss = lseV - vL;
      float corr = (bi == L) ? 1.0f : 0.0f;
      if ((base_b + k) & 1) { l1 += loss; c1 += corr; }
      else                  { l0 += loss; c0 += corr; }
    }
  }

  #pragma unroll
  for (int off = 32; off > 0; off >>= 1) {
    l0 += __shfl_down(l0, off, 64);
    c0 += __shfl_down(c0, off, 64);
    l1 += __shfl_down(l1, off, 64);
    c1 += __shfl_down(c1, off, 64);
  }
  if (lane == 0) { sP[wid][0] = l0; sP[wid][1] = c0; sP[wid][2] = l1; sP[wid][3] = c1; }
  __syncthreads();
  if (t == 0) {
    atomicAdd(&accum[0], sP[0][0]+sP[1][0]+sP[2][0]+sP[3][0]);
    atomicAdd(&accum[1], sP[0][1]+sP[1][1]+sP[2][1]+sP[3][1]);
    atomicAdd(&accum[2], sP[0][2]+sP[1][2]+sP[2][2]+sP[3][2]);
    atomicAdd(&accum[3], sP[0][3]+sP[1][3]+sP[2][3]+sP[3][3]);
    __threadfence();
    int old = atomicAdd(counter, 1);
    if (old == (int)gridDim.x - 1) {       // last block finalizes
      float L0 = atomicAdd(&accum[0], 0.0f);
      float C0 = atomicAdd(&accum[1], 0.0f);
      float L1 = atomicAdd(&accum[2], 0.0f);
      float C1 = atomicAdd(&accum[3], 0.0f);
      float n = (float)(NUM_POS/2);   // 1024
      out[0] = L0 / n;
      out[1] = C0;
      out[2] = n + 1e-6f;
      out[3] = L1 / n;
      out[4] = C1;
      out[5] = n + 1e-6f;
    }
  }
}

// ---------------------------------------------------------------------------
extern "C" void kernel_launch(void* const* d_in, const int* in_sizes, int n_in,
                              void* d_out, int out_size, void* d_ws, size_t ws_size,
                              hipStream_t stream)
{
  const float* es   = (const float*)d_in[0];
  const float* W    = (const float*)d_in[1];
  const float* bias = (const float*)d_in[2];
  const int*   ind  = (const int*)d_in[3];
  const int*   clc  = (const int*)d_in[4];
  float* out = (float*)d_out;

  char* ws = (char*)d_ws;
  float* accum      = (float*)(ws + 0);                  // 4 floats
  int*   counter    = (int*)(ws + 16);
  int*   pos_cnt    = (int*)(ws + 512);
  int*   seg_id     = (int*)(ws + 8192);                 // B*S
  int*   posSegOff  = (int*)(ws + 40960);                // B*(MAXSEG+1)
  int*   posSeg     = (int*)(ws + 49152);                // B*S
  int*   allowCnt   = (int*)(ws + 81920);                // B*256
  int*   firstAllow = (int*)(ws + 86016);                // B*256
  _Float16* segsum_h = (_Float16*)(ws + 90112);          // 1.5 MB
  _Float16* Wh       = (_Float16*)(ws + 1662976);        // 1.125 MB
  _Float16* Uh       = (_Float16*)(ws + 2842624);        // 1.5 MB

  k_front<<<NSEGSUM + BB + NWCAST, 256, 0, stream>>>(
      es, W, ind, clc, segsum_h, Wh, seg_id, pos_cnt,
      allowCnt, firstAllow, posSegOff, posSeg, accum, counter);
  k_gemmU<<<192, 256, 0, stream>>>(segsum_h, Wh, bias, Uh);
  k_gramtail<<<64, 256, 0, stream>>>(Uh, seg_id, clc, pos_cnt, allowCnt,
                                     firstAllow, posSegOff, posSeg,
                                     accum, counter, out);
}

// Round 8
// 130.781 us; speedup vs baseline: 1.0483x; 1.0483x over previous
//
#include <hip/hip_runtime.h>
#include <math.h>
#include <limits.h>

#define BB 4
#define SS 2048
#define HH 768
#define MAXSEG 256
#define NUM_POS (BB*(SS/4))   // 2048
#define NEG_BIG -1000000000.0f
#define NSEGSUM (BB*MAXSEG)   // 1024
#define NWCAST  576           // 768*768/4 float4s / 256 threads

typedef _Float16 f16x8 __attribute__((ext_vector_type(8)));
typedef _Float16 f16x4 __attribute__((ext_vector_type(4)));
typedef float    f32x4 __attribute__((ext_vector_type(4)));

// 256-thread exclusive scan (4 waves, shfl + LDS). Caller must __syncthreads()
// between consecutive uses (sWave reuse).
__device__ __forceinline__ int blockExclScan(int v, int* sWave, int lane, int wid)
{
  int x = v;
  #pragma unroll
  for (int off = 1; off < 64; off <<= 1) {
    int y = __shfl_up(x, off, 64);
    if (lane >= off) x += y;
  }
  if (lane == 63) sWave[wid] = x;
  __syncthreads();
  int base = 0;
  for (int w = 0; w < wid; w++) base += sWave[w];
  return base + x - v;
}

// ---------------------------------------------------------------------------
// Kernel 1 (front): three independent roles, one dispatch.
//   blocks [0,1024): segment sums with inline boundary computation
//   blocks [1024,1028): per-batch scan -> seg_id, positive buckets, accum zero
//   blocks [1028,1604): W f32->f16 cast
// ---------------------------------------------------------------------------
__global__ __launch_bounds__(256) void k_front(
    const float* __restrict__ es, const float* __restrict__ W,
    const int* __restrict__ ind, const int* __restrict__ clc,
    _Float16* __restrict__ segsum_h, _Float16* __restrict__ Wh,
    int* __restrict__ seg_id, int* __restrict__ pos_cnt,
    int* __restrict__ allowCnt, int* __restrict__ firstAllow,
    int* __restrict__ posSegOff, int* __restrict__ posSeg,
    float* __restrict__ accum, int* __restrict__ counter)
{
  int t = threadIdx.x;
  int lane = t & 63, wid = t >> 6;
  int blk = blockIdx.x;

  __shared__ int sInd[SS];
  __shared__ int sWave[4];
  __shared__ int sAC[MAXSEG];
  __shared__ int sFA[MAXSEG];
  __shared__ int sStEn[2];

  if (blk >= NSEGSUM + BB) {
    // ---- W cast ----
    int idx = (blk - NSEGSUM - BB)*256 + t;     // float4 index; 147456 total
    float4 v = ((const float4*)W)[idx];
    f16x4 h;
    h[0] = (_Float16)v.x; h[1] = (_Float16)v.y;
    h[2] = (_Float16)v.z; h[3] = (_Float16)v.w;
    *(f16x4*)(Wh + (size_t)idx*4) = h;
    return;
  }

  if (blk < NSEGSUM) {
    // ---- segment sum for (b, s), boundaries computed inline ----
    int b = blk >> 8, s = blk & 255;
    for (int i = t; i < SS; i += 256) sInd[i] = ind[b*SS + i];
    if (t == 0) { sStEn[0] = SS; sStEn[1] = SS; }
    __syncthreads();
    int i0 = t * 8;
    int f[8]; int lsum = 0;
    #pragma unroll
    for (int u = 0; u < 8; u++) {
      int i = i0 + u;
      f[u] = (i == 0) ? 0 : (sInd[i] != sInd[i-1]);
      lsum += f[u];
    }
    int run = blockExclScan(lsum, sWave, lane, wid);
    #pragma unroll
    for (int u = 0; u < 8; u++) {
      int i = i0 + u;
      run += f[u];
      if (run == s   && (f[u] || i == 0)) sStEn[0] = i;   // start of segment s
      if (run == s+1 && f[u])             sStEn[1] = i;   // start of segment s+1
    }
    __syncthreads();
    int st = sStEn[0], en = sStEn[1];
    float4 acc = {0.f, 0.f, 0.f, 0.f};
    if (t < 192 && st < SS) {          // st==SS => segment doesn't exist -> zeros
      const float* basep = es + (size_t)b*SS*HH + t*4;
      for (int i = st; i < en; i++) {
        float4 v = *(const float4*)(basep + (size_t)i*HH);
        acc.x += v.x; acc.y += v.y; acc.z += v.z; acc.w += v.w;
      }
    }
    if (t < 192) {
      f16x4 h;
      h[0] = (_Float16)acc.x; h[1] = (_Float16)acc.y;
      h[2] = (_Float16)acc.z; h[3] = (_Float16)acc.w;
      *(f16x4*)(segsum_h + ((size_t)b*MAXSEG + s)*HH + t*4) = h;
    }
    return;
  }

  // ---- per-batch scan (blocks 1024..1027) ----
  int b = blk - NSEGSUM;
  if (b == 0 && t < 4) accum[t] = 0.f;
  if (b == 0 && t == 4) *counter = 0;
  for (int i = t; i < SS; i += 256) sInd[i] = ind[b*SS + i];
  sAC[t] = 0; sFA[t] = INT_MAX;
  __syncthreads();

  int i0 = t * 8;
  int f[8], cv[8];
  int lsum = 0;
  #pragma unroll
  for (int u = 0; u < 8; u++) {
    int i = i0 + u;
    f[u] = (i == 0) ? 0 : (sInd[i] != sInd[i-1]);
    cv[u] = clc[b*SS + i];
    lsum += f[u];
  }
  int run = blockExclScan(lsum, sWave, lane, wid);
  int rid[8];
  #pragma unroll
  for (int u = 0; u < 8; u++) {
    run += f[u];
    rid[u] = run;
    seg_id[b*SS + i0 + u] = run;
  }

  // allowed-column stats per segment
  #pragma unroll
  for (int u = 0; u < 8; u++) {
    if (cv[u] < 0) {
      atomicAdd(&sAC[rid[u]], 1);
      atomicMin(&sFA[rid[u]], i0 + u);
    }
  }
  __syncthreads();
  allowCnt[b*MAXSEG + t]   = sAC[t];
  firstAllow[b*MAXSEG + t] = sFA[t];
  __syncthreads();

  // positive ranks (local k within batch)
  int p[8], kk[8];
  int psum = 0;
  #pragma unroll
  for (int u = 0; u < 8; u++) { p[u] = (cv[u] > 0) ? 1 : 0; psum += p[u]; }
  int rank = blockExclScan(psum, sWave, lane, wid);
  #pragma unroll
  for (int u = 0; u < 8; u++) {
    kk[u] = rank;
    if (p[u]) rank++;
  }
  if (t == 255) pos_cnt[b] = rank;
  __syncthreads();

  // bucket positives by segment
  sAC[t] = 0;
  __syncthreads();
  #pragma unroll
  for (int u = 0; u < 8; u++) if (p[u]) atomicAdd(&sAC[rid[u]], 1);
  __syncthreads();
  int cnt = sAC[t];
  int off = blockExclScan(cnt, sWave, lane, wid);
  posSegOff[b*(MAXSEG+1) + t] = off;
  if (t == 255) posSegOff[b*(MAXSEG+1) + 256] = off + cnt;
  __syncthreads();
  sFA[t] = off;                 // scatter cursor
  __syncthreads();
  #pragma unroll
  for (int u = 0; u < 8; u++) {
    if (p[u]) {
      int pos = atomicAdd(&sFA[rid[u]], 1);
      posSeg[b*SS + pos] = (kk[u] << 16) | (i0 + u);
    }
  }
}

// ---------------------------------------------------------------------------
// Kernel 2: U = tanh(segsum @ W^T + bias), f16 MFMA, direct-global fragments.
// Wave = 32x32 tile (2x2 of 16x16x32). 768 tiles -> 192 blocks.
// ---------------------------------------------------------------------------
__global__ __launch_bounds__(256) void k_gemmU(
    const _Float16* __restrict__ Ah, const _Float16* __restrict__ Wh,
    const float* __restrict__ bias, _Float16* __restrict__ Uh)
{
  int tid = threadIdx.x;
  int w = tid >> 6, lane = tid & 63;
  int tile = blockIdx.x*4 + w;          // 0..767 over 32 x 24 tiles
  int tm = tile / 24, tn = tile % 24;
  int rb = tm*32, cb = tn*32;
  int m0 = lane & 15, quad = lane >> 4;
  const _Float16* A0 = Ah + (size_t)(rb + m0)*HH + quad*8;
  const _Float16* A1 = A0 + (size_t)16*HH;
  const _Float16* B0 = Wh + (size_t)(cb + m0)*HH + quad*8;
  const _Float16* B1 = B0 + (size_t)16*HH;
  f32x4 acc00 = {0.f,0.f,0.f,0.f}, acc01 = {0.f,0.f,0.f,0.f};
  f32x4 acc10 = {0.f,0.f,0.f,0.f}, acc11 = {0.f,0.f,0.f,0.f};
  #pragma unroll 4
  for (int k0 = 0; k0 < HH; k0 += 32) {
    f16x8 a0 = *(const f16x8*)(A0 + k0);
    f16x8 a1 = *(const f16x8*)(A1 + k0);
    f16x8 b0 = *(const f16x8*)(B0 + k0);
    f16x8 b1 = *(const f16x8*)(B1 + k0);
    acc00 = __builtin_amdgcn_mfma_f32_16x16x32_f16(a0, b0, acc00, 0, 0, 0);
    acc01 = __builtin_amdgcn_mfma_f32_16x16x32_f16(a0, b1, acc01, 0, 0, 0);
    acc10 = __builtin_amdgcn_mfma_f32_16x16x32_f16(a1, b0, acc10, 0, 0, 0);
    acc11 = __builtin_amdgcn_mfma_f32_16x16x32_f16(a1, b1, acc11, 0, 0, 0);
  }
  float bc0 = bias[cb + m0], bc1 = bias[cb + 16 + m0];
  int r0 = rb + quad*4;
  #pragma unroll
  for (int i = 0; i < 4; i++) {
    Uh[(size_t)(r0+i)*HH    + cb + m0]      = (_Float16)tanhf(acc00[i] + bc0);
    Uh[(size_t)(r0+i)*HH    + cb + 16 + m0] = (_Float16)tanhf(acc01[i] + bc1);
    Uh[(size_t)(r0+16+i)*HH + cb + m0]      = (_Float16)tanhf(acc10[i] + bc0);
    Uh[(size_t)(r0+16+i)*HH + cb + 16 + m0] = (_Float16)tanhf(acc11[i] + bc1);
  }
}

// ---------------------------------------------------------------------------
// Kernel 3: Gram G[b] = U[b] U[b]^T, f16 MFMA. Wave = one 16x16 tile.
// 1024 independent wave-tiles -> 256 blocks (max parallelism).
// ---------------------------------------------------------------------------
__global__ __launch_bounds__(256) void k_gram(
    const _Float16* __restrict__ Uh, float* __restrict__ G)
{
  int tid = threadIdx.x;
  int w = tid >> 6, lane = tid & 63;
  int tile = blockIdx.x*4 + w;          // 0..1023
  int b = tile >> 8, rem = tile & 255;
  int rb = (rem >> 4)*16, cb = (rem & 15)*16;
  int m0 = lane & 15, quad = lane >> 4;
  const _Float16* Ub = Uh + (size_t)b*MAXSEG*HH;
  const _Float16* A0 = Ub + (size_t)(rb + m0)*HH + quad*8;
  const _Float16* B0 = Ub + (size_t)(cb + m0)*HH + quad*8;
  f32x4 acc = {0.f,0.f,0.f,0.f};
  #pragma unroll 4
  for (int k0 = 0; k0 < HH; k0 += 32) {
    f16x8 a  = *(const f16x8*)(A0 + k0);
    f16x8 bb = *(const f16x8*)(B0 + k0);
    acc = __builtin_amdgcn_mfma_f32_16x16x32_f16(a, bb, acc, 0, 0, 0);
  }
  float* Gb = G + (size_t)b*MAXSEG*MAXSEG;
  int r0 = rb + quad*4;
  #pragma unroll
  for (int i = 0; i < 4; i++)
    Gb[(size_t)(r0+i)*MAXSEG + cb + m0] = acc[i];
}

// ---------------------------------------------------------------------------
// Kernel 4: per-(b,seg) wave: logsumexp + argmax + bucketed positive losses;
// block reduce -> 4 atomics; last block finalizes the 6 outputs. 256 blocks.
// ---------------------------------------------------------------------------
__global__ __launch_bounds__(256) void k_tail(
    const float* __restrict__ G, const int* __restrict__ seg_id,
    const int* __restrict__ clc, const int* __restrict__ pos_cnt,
    const int* __restrict__ allowCnt, const int* __restrict__ firstAllow,
    const int* __restrict__ posSegOff, const int* __restrict__ posSeg,
    float* __restrict__ accum, int* __restrict__ counter,
    float* __restrict__ out)
{
  __shared__ float sP[4][4];   // [wave][l0,c0,l1,c1]
  int t = threadIdx.x;
  int lane = t & 63, wid = t >> 6;
  int row = blockIdx.x * 4 + wid;
  int b = row >> 8, si = row & 255;

  const float* g = G + ((size_t)b*MAXSEG + si)*MAXSEG;
  const int* ac = allowCnt + b*MAXSEG;
  const int* fa = firstAllow + b*MAXSEG;
  float gv[4]; int av[4], fv[4];
  #pragma unroll
  for (int q = 0; q < 4; q++) {
    int s2 = lane + 64*q;
    gv[q] = g[s2]; av[q] = ac[s2]; fv[q] = fa[s2];
  }
  // max over allowed segments
  float m = -INFINITY;
  #pragma unroll
  for (int q = 0; q < 4; q++) if (av[q] > 0) m = fmaxf(m, gv[q]);
  #pragma unroll
  for (int off = 32; off > 0; off >>= 1) m = fmaxf(m, __shfl_xor(m, off, 64));
  // weighted exp-sum (masked cols underflow to exactly 0, as in reference)
  float s = 0.f;
  #pragma unroll
  for (int q = 0; q < 4; q++) if (av[q] > 0) s += (float)av[q] * expf(gv[q] - m);
  #pragma unroll
  for (int off = 32; off > 0; off >>= 1) s += __shfl_xor(s, off, 64);
  // first-occurrence argmax
  float bv = -INFINITY; int bi = INT_MAX;
  #pragma unroll
  for (int q = 0; q < 4; q++) {
    if (av[q] > 0 && (gv[q] > bv || (gv[q] == bv && fv[q] < bi))) { bv = gv[q]; bi = fv[q]; }
  }
  #pragma unroll
  for (int off = 32; off > 0; off >>= 1) {
    float ov = __shfl_xor(bv, off, 64);
    int   oi = __shfl_xor(bi, off, 64);
    if (ov > bv || (ov == bv && oi < bi)) { bv = ov; bi = oi; }
  }
  float lseV = m + logf(s);

  // positives belonging to segment si (empty for nonexistent segments)
  int base_b = 0;
  for (int x = 0; x < b; x++) base_b += pos_cnt[x];
  int st = posSegOff[b*(MAXSEG+1) + si];
  int en = posSegOff[b*(MAXSEG+1) + si + 1];
  float l0 = 0.f, c0 = 0.f, l1 = 0.f, c1 = 0.f;
  for (int pp = st + lane; pp < en; pp += 64) {
    int e = posSeg[b*SS + pp];
    int i = e & 0xFFFF, k = e >> 16;
    int L = clc[b*SS + i];
    int sL = seg_id[b*SS + L];
    float vL = g[sL] + (clc[b*SS + L] < 0 ? 0.0f : NEG_BIG);
    float loss = lseV - vL;
    float corr = (bi == L) ? 1.0f : 0.0f;
    if ((base_b + k) & 1) { l1 += loss; c1 += corr; }
    else                  { l0 += loss; c0 += corr; }
  }

  #pragma unroll
  for (int off = 32; off > 0; off >>= 1) {
    l0 += __shfl_down(l0, off, 64);
    c0 += __shfl_down(c0, off, 64);
    l1 += __shfl_down(l1, off, 64);
    c1 += __shfl_down(c1, off, 64);
  }
  if (lane == 0) { sP[wid][0] = l0; sP[wid][1] = c0; sP[wid][2] = l1; sP[wid][3] = c1; }
  __syncthreads();
  if (t == 0) {
    atomicAdd(&accum[0], sP[0][0]+sP[1][0]+sP[2][0]+sP[3][0]);
    atomicAdd(&accum[1], sP[0][1]+sP[1][1]+sP[2][1]+sP[3][1]);
    atomicAdd(&accum[2], sP[0][2]+sP[1][2]+sP[2][2]+sP[3][2]);
    atomicAdd(&accum[3], sP[0][3]+sP[1][3]+sP[2][3]+sP[3][3]);
    __threadfence();
    int old = atomicAdd(counter, 1);
    if (old == (int)gridDim.x - 1) {       // last block finalizes
      float L0 = atomicAdd(&accum[0], 0.0f);
      float C0 = atomicAdd(&accum[1], 0.0f);
      float L1 = atomicAdd(&accum[2], 0.0f);
      float C1 = atomicAdd(&accum[3], 0.0f);
      float n = (float)(NUM_POS/2);   // 1024
      out[0] = L0 / n;
      out[1] = C0;
      out[2] = n + 1e-6f;
      out[3] = L1 / n;
      out[4] = C1;
      out[5] = n + 1e-6f;
    }
  }
}

// ---------------------------------------------------------------------------
extern "C" void kernel_launch(void* const* d_in, const int* in_sizes, int n_in,
                              void* d_out, int out_size, void* d_ws, size_t ws_size,
                              hipStream_t stream)
{
  const float* es   = (const float*)d_in[0];
  const float* W    = (const float*)d_in[1];
  const float* bias = (const float*)d_in[2];
  const int*   ind  = (const int*)d_in[3];
  const int*   clc  = (const int*)d_in[4];
  float* out = (float*)d_out;

  char* ws = (char*)d_ws;
  float* accum      = (float*)(ws + 0);                  // 4 floats
  int*   counter    = (int*)(ws + 16);
  int*   pos_cnt    = (int*)(ws + 512);
  int*   seg_id     = (int*)(ws + 8192);                 // B*S
  int*   posSegOff  = (int*)(ws + 40960);                // B*(MAXSEG+1)
  int*   posSeg     = (int*)(ws + 49152);                // B*S
  int*   allowCnt   = (int*)(ws + 81920);                // B*256
  int*   firstAllow = (int*)(ws + 86016);                // B*256
  _Float16* segsum_h = (_Float16*)(ws + 90112);          // 1.5 MB
  _Float16* Wh       = (_Float16*)(ws + 1662976);        // 1.125 MB
  _Float16* Uh       = (_Float16*)(ws + 2842624);        // 1.5 MB
  float*    G        = (float*)(ws + 4415488);           // 1 MB

  k_front<<<NSEGSUM + BB + NWCAST, 256, 0, stream>>>(
      es, W, ind, clc, segsum_h, Wh, seg_id, pos_cnt,
      allowCnt, firstAllow, posSegOff, posSeg, accum, counter);
  k_gemmU<<<192, 256, 0, stream>>>(segsum_h, Wh, bias, Uh);
  k_gram<<<256, 256, 0, stream>>>(Uh, G);
  k_tail<<<256, 256, 0, stream>>>(G, seg_id, clc, pos_cnt, allowCnt,
                                  firstAllow, posSegOff, posSeg,
                                  accum, counter, out);
}